// Round 4
// baseline (688.271 us; speedup 1.0000x reference)
//
#include <hip/hip_runtime.h>
#include <hip/hip_bf16.h>

#define B_ 8
#define C_ 256
#define H_ 128
#define W_ 128
#define HW_ 16384
#define CHW_ (C_ * HW_)
#define NH_ 8
#define HD_ 32
#define NTOT (B_ * CHW_)   // 33,554,432

typedef short short8 __attribute__((ext_vector_type(8)));
typedef float f32x4 __attribute__((ext_vector_type(4)));

// ---------------- weight fp32 -> bf16 convert ----------------
__global__ __launch_bounds__(256) void wconv_kernel(const float* __restrict__ vw,
                                                    const float* __restrict__ ow,
                                                    __hip_bfloat16* __restrict__ wvb,
                                                    __hip_bfloat16* __restrict__ wob) {
    int i = blockIdx.x * 256 + threadIdx.x;   // 65536
    wvb[i] = __float2bfloat16(vw[i]);
    wob[i] = __float2bfloat16(ow[i]);
}

// ---------------- x [b][c][p] fp32 -> xT [b][p][c] bf16 (LDS-tiled transpose) ----------------
__global__ __launch_bounds__(256) void xt_kernel(const float* __restrict__ x,
                                                 __hip_bfloat16* __restrict__ xT) {
    __shared__ float tile[64][68];
    int t = threadIdx.x;
    int p0 = blockIdx.x * 64, c0 = blockIdx.y * 64, b = blockIdx.z;
    const float* xb = x + ((size_t)b * C_ + c0) * HW_ + p0;
#pragma unroll
    for (int l = 0; l < 4; ++l) {
        int idx = t + 256 * l;
        int row = idx >> 4, cf = idx & 15;
        float4 v = *(const float4*)&xb[(size_t)row * HW_ + cf * 4];
        *(float4*)&tile[row][cf * 4] = v;
    }
    __syncthreads();
    __hip_bfloat16* op = xT + ((size_t)b * HW_ + p0) * C_ + c0;
#pragma unroll
    for (int l = 0; l < 2; ++l) {
        int idx = t + 256 * l;
        int p = idx & 63, oct = idx >> 6;    // oct 0..7
        __hip_bfloat16 arr[8];
#pragma unroll
        for (int j = 0; j < 8; ++j) arr[j] = __float2bfloat16(tile[oct * 8 + j][p]);
        *(int4*)(op + (size_t)p * C_ + oct * 8) = *(int4*)arr;
    }
}

// ---------------- FUSED dwconv3x3 + partial offset projection ----------------
__global__ __launch_bounds__(256) void fused_offset_kernel(const float* __restrict__ x,
                                                           const float* __restrict__ dww,
                                                           const float* __restrict__ offw,
                                                           float* __restrict__ partials) {
    __shared__ float xt[4][10][136];   // 4 ch, 10 halo rows, col+4 shift, pad
    __shared__ float wT[32][16];
    __shared__ float wd[32][9];
    int t = threadIdx.x;
    int rt = blockIdx.x, cg = blockIdx.y, b = blockIdx.z;
    int h0 = rt * 8, c0 = cg * 32;
    for (int i = t; i < 512; i += 256) { int o = i >> 5, c = i & 31; wT[c][o] = offw[o * 256 + c0 + c]; }
    for (int i = t; i < 288; i += 256) { wd[i / 9][i % 9] = dww[(c0 + i / 9) * 9 + i % 9]; }
    const float* xb = x + ((size_t)b * C_ + c0) * HW_;
    int col = t & 127;
    int sb = (t >> 7) * 4;             // row-strip base 0 or 4
    float acc[4][16] = {};
    for (int cc0 = 0; cc0 < 32; cc0 += 4) {
        __syncthreads();
#pragma unroll
        for (int l = 0; l < 5; ++l) {
            int idx = t + 256 * l;             // 0..1279
            int pr = idx >> 5, c4 = idx & 31;
            int cc = pr / 10, r = pr - cc * 10;
            int gh = h0 - 1 + r;
            float4 v = make_float4(0.f, 0.f, 0.f, 0.f);
            if (gh >= 0 && gh < H_)
                v = *(const float4*)&xb[(size_t)(cc0 + cc) * HW_ + gh * W_ + c4 * 4];
            *(float4*)&xt[cc][r][4 + c4 * 4] = v;
        }
        if (t < 80) { int pr = t >> 1, side = t & 1; xt[pr / 10][pr % 10][side ? 132 : 3] = 0.f; }
        __syncthreads();
#pragma unroll
        for (int cc = 0; cc < 4; ++cc) {
            float win[6][3];
#pragma unroll
            for (int rr = 0; rr < 6; ++rr)
#pragma unroll
                for (int kk = 0; kk < 3; ++kk)
                    win[rr][kk] = xt[cc][sb + rr][col + 3 + kk];
            float w9[9];
#pragma unroll
            for (int k9 = 0; k9 < 9; ++k9) w9[k9] = wd[cc0 + cc][k9];
#pragma unroll
            for (int j = 0; j < 4; ++j) {
                float s = 0.f;
#pragma unroll
                for (int ky = 0; ky < 3; ++ky)
#pragma unroll
                    for (int kx = 0; kx < 3; ++kx)
                        s += win[j + ky][kx] * w9[ky * 3 + kx];
#pragma unroll
                for (int o = 0; o < 16; ++o) acc[j][o] += s * wT[cc0 + cc][o];
            }
        }
    }
    float* pb = partials + (size_t)(cg * 8 + b) * 16 * HW_;
#pragma unroll
    for (int o = 0; o < 16; ++o)
#pragma unroll
        for (int j = 0; j < 4; ++j)
            pb[(size_t)o * HW_ + (h0 + sb + j) * W_ + col] = acc[j][o];
}

// ---------------- sum 8 partials + bias + tanh ----------------
__global__ __launch_bounds__(256) void offreduce_kernel(const float* __restrict__ partials,
                                                        const float* __restrict__ offb,
                                                        float* __restrict__ off_buf) {
    int i = blockIdx.x * 256 + threadIdx.x;     // 0..2097151 over [b][o][p]
    float s = 0.f;
#pragma unroll
    for (int cg = 0; cg < 8; ++cg) s += partials[(size_t)cg * 2097152 + i];
    int o = (i >> 14) & 15;
    off_buf[i] = tanhf(s + offb[o]) * 0.5f;
}

// ---------------- bf16 MFMA GEMM: Y[b](256 x HW) = W(256x256) * X[b], X given as X^T [p][c] ----------------
// Concurrency-first structure: n-tile 64 -> 32KB LDS (4 blocks/CU), VGPR<=128 via
// __launch_bounds__(256,4) (16 waves/CU). B staged once per block (XOR-swizzled both sides),
// single barrier, A fragments loaded per-k-step from L2-hot W (128KB), 8 barrier-free steps.
// TRANS: write Y^T [n][c] as bf16 (for sampling).  STATS: accumulate group sum/sumsq.
template<bool TRANS, bool STATS>
__global__ __launch_bounds__(256, 4) void mfma_gemm(const __hip_bfloat16* __restrict__ Wb,
                                                    const __hip_bfloat16* __restrict__ Xt,
                                                    void* __restrict__ Y,
                                                    float* __restrict__ stats) {
    __shared__ __align__(16) short Bs[64 * 256];   // 32KB: [n][k] 512B rows, XOR-swizzled 16B slots
    int t = threadIdx.x;
    int wave = t >> 6, lane = t & 63;
    int quad = lane >> 4, l16 = lane & 15;
    int b = blockIdx.z;
    int n0 = blockIdx.x * 64, m0 = blockIdx.y * 128;
    const short* Wp = (const short*)Wb + (size_t)m0 * 256;
    const short* Xp = (const short*)Xt + ((size_t)b * HW_ + n0) * 256;

    // ---- stage B: 64 rows x 512B; thread: slot s=t&31, rows (t>>5)+8i ----
    int s = t & 31;
    int rg = t >> 5;
    int4 st[8];
#pragma unroll
    for (int i = 0; i < 8; ++i)
        st[i] = *(const int4*)(Xp + (size_t)(rg + i * 8) * 256 + s * 8);
#pragma unroll
    for (int i = 0; i < 8; ++i) {
        int n = rg + i * 8;
        int sw = (s & 24) | ((s ^ n) & 7);
        *(int4*)((char*)Bs + n * 512 + sw * 16) = st[i];
    }

    f32x4 acc[2][4];
#pragma unroll
    for (int mt = 0; mt < 2; ++mt)
#pragma unroll
        for (int nt = 0; nt < 4; ++nt) acc[mt][nt] = (f32x4){0.f, 0.f, 0.f, 0.f};

    __syncthreads();   // the ONLY barrier: B tile resident

#pragma unroll
    for (int ks = 0; ks < 8; ++ks) {
        short8 af[2];
#pragma unroll
        for (int mt = 0; mt < 2; ++mt) {
            int m = wave * 32 + mt * 16 + l16;
            af[mt] = *(const short8*)(Wp + (size_t)m * 256 + ks * 32 + quad * 8);
        }
        short8 bf[4];
#pragma unroll
        for (int nt = 0; nt < 4; ++nt) {
            int n = nt * 16 + l16;
            int slot = ks * 4 + quad;
            int sw = (slot & 24) | ((slot ^ n) & 7);
            bf[nt] = *(const short8*)((const char*)Bs + n * 512 + sw * 16);
        }
#pragma unroll
        for (int mt = 0; mt < 2; ++mt)
#pragma unroll
            for (int nt = 0; nt < 4; ++nt)
                acc[mt][nt] = __builtin_amdgcn_mfma_f32_16x16x32_bf16(af[mt], bf[nt], acc[mt][nt], 0, 0, 0);
    }

    if constexpr (TRANS) {
        // Y^T [n][c] bf16: acc[mt][nt] = 4 consecutive channels at one n -> 8B store
        __hip_bfloat16* Yb = (__hip_bfloat16*)Y + (size_t)b * CHW_;
#pragma unroll
        for (int mt = 0; mt < 2; ++mt)
#pragma unroll
            for (int nt = 0; nt < 4; ++nt) {
                int m = m0 + wave * 32 + mt * 16 + quad * 4;
                int n = n0 + nt * 16 + l16;
                __hip_bfloat16 arr[4];
#pragma unroll
                for (int r = 0; r < 4; ++r) arr[r] = __float2bfloat16(acc[mt][nt][r]);
                *(int2*)((__hip_bfloat16*)Yb + (size_t)n * C_ + m) = *(int2*)arr;
            }
    } else {
        float* Yb = (float*)Y + (size_t)b * CHW_;
#pragma unroll
        for (int mt = 0; mt < 2; ++mt)
#pragma unroll
            for (int nt = 0; nt < 4; ++nt)
#pragma unroll
                for (int r = 0; r < 4; ++r) {
                    int m = m0 + wave * 32 + mt * 16 + quad * 4 + r;
                    int n = n0 + nt * 16 + l16;
                    Yb[(size_t)m * HW_ + n] = acc[mt][nt][r];
                }
    }
    if constexpr (STATS) {
        // each wave's m-range is exactly one 32-channel group: grp = b*8 + m0/32 + wave
        float s1 = 0.f, s2 = 0.f;
#pragma unroll
        for (int mt = 0; mt < 2; ++mt)
#pragma unroll
            for (int nt = 0; nt < 4; ++nt)
#pragma unroll
                for (int r = 0; r < 4; ++r) {
                    float v = acc[mt][nt][r];
                    s1 += v;
                    s2 += v * v;
                }
#pragma unroll
        for (int o = 32; o; o >>= 1) {
            s1 += __shfl_down(s1, o);
            s2 += __shfl_down(s2, o);
        }
        if (lane == 0) {
            int grp = b * NH_ + (m0 >> 5) + wave;
            atomicAdd(&stats[grp * 2 + 0], s1);
            atomicAdd(&stats[grp * 2 + 1], s2);
        }
    }
}

// ---------------- deformable bilinear sampling from V^T bf16 [b][p][c] -> sampledT bf16 [b][p][c] ----------------
// block 256 = 8 pixels x 8 heads x 4 chunks; 4 consecutive lanes = the 4x16B bf16 chunks of one
// (pixel,head) 64B tap segment -> every load reads contiguous 64B lines.
__global__ __launch_bounds__(256) void sample_kernel(const __hip_bfloat16* __restrict__ VT,
                                                     const float* __restrict__ off,
                                                     __hip_bfloat16* __restrict__ sT) {
    int t = threadIdx.x;
    int chunk = t & 3;                 // 16B (8ch) chunk within head's 64B segment
    int g = t >> 2;                    // 0..63 = pixel_sub*8 + head
    int head = g & 7;
    int p = blockIdx.x * 8 + (g >> 3);
    int b = blockIdx.z;
    int h = p >> 7, w = p & 127;
    const float* ob = off + ((size_t)b * 16 + head * 2) * HW_ + p;
    float dy = ob[0], dx = ob[HW_];    // broadcast within 4-lane group
    float gy = h * (2.0f / 127.0f) - 1.0f;
    float gx = w * (2.0f / 127.0f) - 1.0f;
    float sx = fminf(fmaxf(gx + dx, -1.0f), 1.0f);
    float sy = fminf(fmaxf(gy + dy, -1.0f), 1.0f);
    float ix = (sx + 1.0f) * 0.5f * 127.0f;
    float iy = (sy + 1.0f) * 0.5f * 127.0f;
    float x0f = floorf(ix), y0f = floorf(iy);
    float wx = ix - x0f, wy = iy - y0f;
    int x0 = min(max((int)x0f, 0), 127);
    int x1 = min((int)x0f + 1, 127);
    int y0 = min(max((int)y0f, 0), 127);
    int y1 = min((int)y0f + 1, 127);
    float w00 = (1.f - wx) * (1.f - wy), w01 = wx * (1.f - wy);
    float w10 = (1.f - wx) * wy, w11 = wx * wy;
    const short* Vb = (const short*)VT + (size_t)b * CHW_ + head * 32 + chunk * 8;
    short8 v00 = *(const short8*)(Vb + (size_t)(y0 * W_ + x0) * C_);
    short8 v01 = *(const short8*)(Vb + (size_t)(y0 * W_ + x1) * C_);
    short8 v10 = *(const short8*)(Vb + (size_t)(y1 * W_ + x0) * C_);
    short8 v11 = *(const short8*)(Vb + (size_t)(y1 * W_ + x1) * C_);
    __hip_bfloat16 arr[8];
#pragma unroll
    for (int j = 0; j < 8; ++j) {
        float f = __bfloat162float(((const __hip_bfloat16*)&v00)[j]) * w00 +
                  __bfloat162float(((const __hip_bfloat16*)&v01)[j]) * w01 +
                  __bfloat162float(((const __hip_bfloat16*)&v10)[j]) * w10 +
                  __bfloat162float(((const __hip_bfloat16*)&v11)[j]) * w11;
        arr[j] = __float2bfloat16(f);
    }
    __hip_bfloat16* op = sT + ((size_t)b * HW_ + p) * C_ + head * 32 + chunk * 8;
    *(int4*)op = *(int4*)arr;
}

// ---------------- normalize + affine + residual (float4) ----------------
__global__ __launch_bounds__(256) void final_kernel(const float* __restrict__ x,
                                                    const float* __restrict__ stats,
                                                    const float* __restrict__ gamma,
                                                    const float* __restrict__ beta,
                                                    float* __restrict__ out) {
    int idx = (blockIdx.x * 256 + threadIdx.x) * 4;
    int c = (idx >> 14) & 255;
    int b = idx >> 22;
    int grp = b * NH_ + (c >> 5);
    const float invN = 1.0f / (float)(HD_ * HW_);
    float mu = stats[grp * 2 + 0] * invN;
    float var = stats[grp * 2 + 1] * invN - mu * mu;
    float r = rsqrtf(var + 1e-5f);
    float g = gamma[c], be = beta[c];
    float4 v = *(const float4*)&out[idx];
    float4 xv = *(const float4*)&x[idx];
    float4 o;
    o.x = xv.x + (v.x - mu) * r * g + be;
    o.y = xv.y + (v.y - mu) * r * g + be;
    o.z = xv.z + (v.z - mu) * r * g + be;
    o.w = xv.w + (v.w - mu) * r * g + be;
    *(float4*)&out[idx] = o;
}

extern "C" void kernel_launch(void* const* d_in, const int* in_sizes, int n_in,
                              void* d_out, int out_size, void* d_ws, size_t ws_size,
                              hipStream_t stream) {
    const float* x     = (const float*)d_in[0];
    const float* dww   = (const float*)d_in[1];
    const float* offw  = (const float*)d_in[2];
    const float* offb  = (const float*)d_in[3];
    const float* vw    = (const float*)d_in[4];
    const float* ow    = (const float*)d_in[5];
    const float* gamma = (const float*)d_in[6];
    const float* beta  = (const float*)d_in[7];
    float* out = (float*)d_out;
    float* ws_f = (float*)d_ws;

    // ws layout (floats)
    float* partials = ws_f;                                   // 16,777,216 f
    float* off_buf  = ws_f + 16777216;                        //  2,097,152 f
    float* stats    = ws_f + 18874368;                        //        256 f
    __hip_bfloat16* wvb = (__hip_bfloat16*)(ws_f + 18874624); //  65,536 bf16
    __hip_bfloat16* wob = wvb + 65536;                        //  65,536 bf16
    __hip_bfloat16* xT  = (__hip_bfloat16*)(ws_f + 18940160); //  33,554,432 bf16
    __hip_bfloat16* sT  = (__hip_bfloat16*)partials;          //  alias region A (partials dead after offreduce)
    __hip_bfloat16* vT  = (__hip_bfloat16*)out;               //  V^T bf16 staging in d_out (64MB of 128MB)

    // 1. weight converts + x transpose to bf16
    wconv_kernel<<<256, 256, 0, stream>>>(vw, ow, wvb, wob);
    xt_kernel<<<dim3(256, 4, 8), 256, 0, stream>>>(x, xT);
    // 2. fused dwconv + partial offset proj
    fused_offset_kernel<<<dim3(16, 8, 8), 256, 0, stream>>>(x, dww, offw, partials);
    offreduce_kernel<<<8192, 256, 0, stream>>>(partials, offb, off_buf);
    // 3. V^T[b][p][c] = (vw * x)^T bf16 (single-barrier MFMA GEMM)
    mfma_gemm<true, false><<<dim3(256, 2, 8), 256, 0, stream>>>(wvb, xT, (void*)vT, nullptr);
    // 4. deformable sampling from V^T bf16 -> sT bf16 [p][c]
    sample_kernel<<<dim3(2048, 1, 8), 256, 0, stream>>>(vT, off_buf, sT);
    // 5. out = ow * sampled + fused group stats -> d_out fp32
    hipMemsetAsync(stats, 0, 128 * sizeof(float), stream);
    mfma_gemm<false, true><<<dim3(256, 2, 8), 256, 0, stream>>>(wob, sT, (void*)out, stats);
    // 6. normalize + residual
    final_kernel<<<NTOT / 1024, 256, 0, stream>>>(x, stats, gamma, beta, out);
}

// Round 5
// 641.944 us; speedup vs baseline: 1.0722x; 1.0722x over previous
//
#include <hip/hip_runtime.h>
#include <hip/hip_bf16.h>

#define B_ 8
#define C_ 256
#define H_ 128
#define W_ 128
#define HW_ 16384
#define CHW_ (C_ * HW_)
#define NH_ 8
#define HD_ 32
#define NTOT (B_ * CHW_)   // 33,554,432

typedef short short8 __attribute__((ext_vector_type(8)));
typedef float f32x4 __attribute__((ext_vector_type(4)));

// ---------------- weight fp32 -> bf16 convert ----------------
__global__ __launch_bounds__(256) void wconv_kernel(const float* __restrict__ vw,
                                                    const float* __restrict__ ow,
                                                    __hip_bfloat16* __restrict__ wvb,
                                                    __hip_bfloat16* __restrict__ wob) {
    int i = blockIdx.x * 256 + threadIdx.x;   // 65536
    wvb[i] = __float2bfloat16(vw[i]);
    wob[i] = __float2bfloat16(ow[i]);
}

// ---------------- x [b][c][p] fp32 -> xT [b][p][c] bf16 (LDS-tiled transpose) ----------------
__global__ __launch_bounds__(256) void xt_kernel(const float* __restrict__ x,
                                                 __hip_bfloat16* __restrict__ xT) {
    __shared__ float tile[64][68];
    int t = threadIdx.x;
    int p0 = blockIdx.x * 64, c0 = blockIdx.y * 64, b = blockIdx.z;
    const float* xb = x + ((size_t)b * C_ + c0) * HW_ + p0;
#pragma unroll
    for (int l = 0; l < 4; ++l) {
        int idx = t + 256 * l;
        int row = idx >> 4, cf = idx & 15;
        float4 v = *(const float4*)&xb[(size_t)row * HW_ + cf * 4];
        *(float4*)&tile[row][cf * 4] = v;
    }
    __syncthreads();
    __hip_bfloat16* op = xT + ((size_t)b * HW_ + p0) * C_ + c0;
#pragma unroll
    for (int l = 0; l < 2; ++l) {
        int idx = t + 256 * l;
        int p = idx & 63, oct = idx >> 6;    // oct 0..7
        __hip_bfloat16 arr[8];
#pragma unroll
        for (int j = 0; j < 8; ++j) arr[j] = __float2bfloat16(tile[oct * 8 + j][p]);
        *(int4*)(op + (size_t)p * C_ + oct * 8) = *(int4*)arr;
    }
}

// ---------------- FUSED dwconv3x3 + partial offset projection ----------------
__global__ __launch_bounds__(256) void fused_offset_kernel(const float* __restrict__ x,
                                                           const float* __restrict__ dww,
                                                           const float* __restrict__ offw,
                                                           float* __restrict__ partials) {
    __shared__ float xt[4][10][136];   // 4 ch, 10 halo rows, col+4 shift, pad
    __shared__ float wT[32][16];
    __shared__ float wd[32][9];
    int t = threadIdx.x;
    int rt = blockIdx.x, cg = blockIdx.y, b = blockIdx.z;
    int h0 = rt * 8, c0 = cg * 32;
    for (int i = t; i < 512; i += 256) { int o = i >> 5, c = i & 31; wT[c][o] = offw[o * 256 + c0 + c]; }
    for (int i = t; i < 288; i += 256) { wd[i / 9][i % 9] = dww[(c0 + i / 9) * 9 + i % 9]; }
    const float* xb = x + ((size_t)b * C_ + c0) * HW_;
    int col = t & 127;
    int sb = (t >> 7) * 4;             // row-strip base 0 or 4
    float acc[4][16] = {};
    for (int cc0 = 0; cc0 < 32; cc0 += 4) {
        __syncthreads();
#pragma unroll
        for (int l = 0; l < 5; ++l) {
            int idx = t + 256 * l;             // 0..1279
            int pr = idx >> 5, c4 = idx & 31;
            int cc = pr / 10, r = pr - cc * 10;
            int gh = h0 - 1 + r;
            float4 v = make_float4(0.f, 0.f, 0.f, 0.f);
            if (gh >= 0 && gh < H_)
                v = *(const float4*)&xb[(size_t)(cc0 + cc) * HW_ + gh * W_ + c4 * 4];
            *(float4*)&xt[cc][r][4 + c4 * 4] = v;
        }
        if (t < 80) { int pr = t >> 1, side = t & 1; xt[pr / 10][pr % 10][side ? 132 : 3] = 0.f; }
        __syncthreads();
#pragma unroll
        for (int cc = 0; cc < 4; ++cc) {
            float win[6][3];
#pragma unroll
            for (int rr = 0; rr < 6; ++rr)
#pragma unroll
                for (int kk = 0; kk < 3; ++kk)
                    win[rr][kk] = xt[cc][sb + rr][col + 3 + kk];
            float w9[9];
#pragma unroll
            for (int k9 = 0; k9 < 9; ++k9) w9[k9] = wd[cc0 + cc][k9];
#pragma unroll
            for (int j = 0; j < 4; ++j) {
                float s = 0.f;
#pragma unroll
                for (int ky = 0; ky < 3; ++ky)
#pragma unroll
                    for (int kx = 0; kx < 3; ++kx)
                        s += win[j + ky][kx] * w9[ky * 3 + kx];
#pragma unroll
                for (int o = 0; o < 16; ++o) acc[j][o] += s * wT[cc0 + cc][o];
            }
        }
    }
    float* pb = partials + (size_t)(cg * 8 + b) * 16 * HW_;
#pragma unroll
    for (int o = 0; o < 16; ++o)
#pragma unroll
        for (int j = 0; j < 4; ++j)
            pb[(size_t)o * HW_ + (h0 + sb + j) * W_ + col] = acc[j][o];
}

// ---------------- sum 8 partials + bias + tanh ----------------
__global__ __launch_bounds__(256) void offreduce_kernel(const float* __restrict__ partials,
                                                        const float* __restrict__ offb,
                                                        float* __restrict__ off_buf) {
    int i = blockIdx.x * 256 + threadIdx.x;     // 0..2097151 over [b][o][p]
    float s = 0.f;
#pragma unroll
    for (int cg = 0; cg < 8; ++cg) s += partials[(size_t)cg * 2097152 + i];
    int o = (i >> 14) & 15;
    off_buf[i] = tanhf(s + offb[o]) * 0.5f;
}

// ---------------- bf16 MFMA GEMM: Y[b](256 x HW) = W(256x256) * X[b], X given as X^T [p][c] ----------------
// Zero-LDS, zero-barrier streaming structure for tiny-K/huge-N:
//  - W fragments for the wave's 32 m-rows x full K=256 preloaded to registers (64 VGPR, L2-hot).
//  - B fragments are NATIVELY contiguous in X^T: [n*512B + ks*64 + quad*16] -> 16B/lane,
//    16 rows x 64B per instruction, loaded global->reg with 2-deep prefetch (triple buffer).
//  - No __syncthreads anywhere: nothing forces a vmcnt drain; loads float early.
// TRANS: write Y^T [n][c] as bf16 (for sampling).  STATS: accumulate group sum/sumsq.
template<bool TRANS, bool STATS>
__global__ __launch_bounds__(256, 2) void mfma_gemm(const __hip_bfloat16* __restrict__ Wb,
                                                    const __hip_bfloat16* __restrict__ Xt,
                                                    void* __restrict__ Y,
                                                    float* __restrict__ stats) {
    int t = threadIdx.x;
    int wave = t >> 6, lane = t & 63;
    int quad = lane >> 4, l16 = lane & 15;
    int b = blockIdx.z;
    int n0 = blockIdx.x * 128, m0 = blockIdx.y * 128;
    const short* Wp = (const short*)Wb + (size_t)(m0 + wave * 32) * 256;
    const short* Xp = (const short*)Xt + ((size_t)b * HW_ + n0) * 256;

    // ---- preload all A fragments (wave's 32 m-rows, full K) ----
    short8 af[8][2];
#pragma unroll
    for (int ks = 0; ks < 8; ++ks)
#pragma unroll
        for (int mt = 0; mt < 2; ++mt)
            af[ks][mt] = *(const short8*)(Wp + (size_t)(mt * 16 + l16) * 256 + ks * 32 + quad * 8);

    // ---- B stream: triple-buffered fragments, prefetch distance 2 ----
    const short* Xl = Xp + (size_t)l16 * 256 + quad * 8;   // lane base; +nt*16*256 per n-tile, +ks*32 per k
    short8 bf[3][8];
#pragma unroll
    for (int pf = 0; pf < 2; ++pf)
#pragma unroll
        for (int nt = 0; nt < 8; ++nt)
            bf[pf][nt] = *(const short8*)(Xl + (size_t)nt * 16 * 256 + pf * 32);

    f32x4 acc[2][8];
#pragma unroll
    for (int mt = 0; mt < 2; ++mt)
#pragma unroll
        for (int nt = 0; nt < 8; ++nt) acc[mt][nt] = (f32x4){0.f, 0.f, 0.f, 0.f};

#pragma unroll
    for (int ks = 0; ks < 8; ++ks) {
        if (ks < 6) {
#pragma unroll
            for (int nt = 0; nt < 8; ++nt)
                bf[(ks + 2) % 3][nt] = *(const short8*)(Xl + (size_t)nt * 16 * 256 + (ks + 2) * 32);
        }
#pragma unroll
        for (int mt = 0; mt < 2; ++mt)
#pragma unroll
            for (int nt = 0; nt < 8; ++nt)
                acc[mt][nt] = __builtin_amdgcn_mfma_f32_16x16x32_bf16(af[ks][mt], bf[ks % 3][nt], acc[mt][nt], 0, 0, 0);
    }

    if constexpr (TRANS) {
        // Y^T [n][c] bf16: acc[mt][nt] = 4 consecutive channels at one n -> 8B store
        __hip_bfloat16* Yb = (__hip_bfloat16*)Y + (size_t)b * CHW_;
#pragma unroll
        for (int mt = 0; mt < 2; ++mt)
#pragma unroll
            for (int nt = 0; nt < 8; ++nt) {
                int m = m0 + wave * 32 + mt * 16 + quad * 4;
                int n = n0 + nt * 16 + l16;
                __hip_bfloat16 arr[4];
#pragma unroll
                for (int r = 0; r < 4; ++r) arr[r] = __float2bfloat16(acc[mt][nt][r]);
                *(int2*)((__hip_bfloat16*)Yb + (size_t)n * C_ + m) = *(int2*)arr;
            }
    } else {
        float* Yb = (float*)Y + (size_t)b * CHW_;
#pragma unroll
        for (int mt = 0; mt < 2; ++mt)
#pragma unroll
            for (int nt = 0; nt < 8; ++nt)
#pragma unroll
                for (int r = 0; r < 4; ++r) {
                    int m = m0 + wave * 32 + mt * 16 + quad * 4 + r;
                    int n = n0 + nt * 16 + l16;
                    Yb[(size_t)m * HW_ + n] = acc[mt][nt][r];
                }
    }
    if constexpr (STATS) {
        // each wave's m-range is exactly one 32-channel group: grp = b*8 + m0/32 + wave
        float s1 = 0.f, s2 = 0.f;
#pragma unroll
        for (int mt = 0; mt < 2; ++mt)
#pragma unroll
            for (int nt = 0; nt < 8; ++nt)
#pragma unroll
                for (int r = 0; r < 4; ++r) {
                    float v = acc[mt][nt][r];
                    s1 += v;
                    s2 += v * v;
                }
#pragma unroll
        for (int o = 32; o; o >>= 1) {
            s1 += __shfl_down(s1, o);
            s2 += __shfl_down(s2, o);
        }
        if (lane == 0) {
            int grp = b * NH_ + (m0 >> 5) + wave;
            atomicAdd(&stats[grp * 2 + 0], s1);
            atomicAdd(&stats[grp * 2 + 1], s2);
        }
    }
}

// ---------------- deformable bilinear sampling from V^T bf16 [b][p][c] -> sampledT bf16 [b][p][c] ----------------
// block 256 = 8 pixels x 8 heads x 4 chunks; 4 consecutive lanes = the 4x16B bf16 chunks of one
// (pixel,head) 64B tap segment -> every load reads contiguous 64B lines.
__global__ __launch_bounds__(256) void sample_kernel(const __hip_bfloat16* __restrict__ VT,
                                                     const float* __restrict__ off,
                                                     __hip_bfloat16* __restrict__ sT) {
    int t = threadIdx.x;
    int chunk = t & 3;                 // 16B (8ch) chunk within head's 64B segment
    int g = t >> 2;                    // 0..63 = pixel_sub*8 + head
    int head = g & 7;
    int p = blockIdx.x * 8 + (g >> 3);
    int b = blockIdx.z;
    int h = p >> 7, w = p & 127;
    const float* ob = off + ((size_t)b * 16 + head * 2) * HW_ + p;
    float dy = ob[0], dx = ob[HW_];    // broadcast within 4-lane group
    float gy = h * (2.0f / 127.0f) - 1.0f;
    float gx = w * (2.0f / 127.0f) - 1.0f;
    float sx = fminf(fmaxf(gx + dx, -1.0f), 1.0f);
    float sy = fminf(fmaxf(gy + dy, -1.0f), 1.0f);
    float ix = (sx + 1.0f) * 0.5f * 127.0f;
    float iy = (sy + 1.0f) * 0.5f * 127.0f;
    float x0f = floorf(ix), y0f = floorf(iy);
    float wx = ix - x0f, wy = iy - y0f;
    int x0 = min(max((int)x0f, 0), 127);
    int x1 = min((int)x0f + 1, 127);
    int y0 = min(max((int)y0f, 0), 127);
    int y1 = min((int)y0f + 1, 127);
    float w00 = (1.f - wx) * (1.f - wy), w01 = wx * (1.f - wy);
    float w10 = (1.f - wx) * wy, w11 = wx * wy;
    const short* Vb = (const short*)VT + (size_t)b * CHW_ + head * 32 + chunk * 8;
    short8 v00 = *(const short8*)(Vb + (size_t)(y0 * W_ + x0) * C_);
    short8 v01 = *(const short8*)(Vb + (size_t)(y0 * W_ + x1) * C_);
    short8 v10 = *(const short8*)(Vb + (size_t)(y1 * W_ + x0) * C_);
    short8 v11 = *(const short8*)(Vb + (size_t)(y1 * W_ + x1) * C_);
    __hip_bfloat16 arr[8];
#pragma unroll
    for (int j = 0; j < 8; ++j) {
        float f = __bfloat162float(((const __hip_bfloat16*)&v00)[j]) * w00 +
                  __bfloat162float(((const __hip_bfloat16*)&v01)[j]) * w01 +
                  __bfloat162float(((const __hip_bfloat16*)&v10)[j]) * w10 +
                  __bfloat162float(((const __hip_bfloat16*)&v11)[j]) * w11;
        arr[j] = __float2bfloat16(f);
    }
    __hip_bfloat16* op = sT + ((size_t)b * HW_ + p) * C_ + head * 32 + chunk * 8;
    *(int4*)op = *(int4*)arr;
}

// ---------------- normalize + affine + residual (float4) ----------------
__global__ __launch_bounds__(256) void final_kernel(const float* __restrict__ x,
                                                    const float* __restrict__ stats,
                                                    const float* __restrict__ gamma,
                                                    const float* __restrict__ beta,
                                                    float* __restrict__ out) {
    int idx = (blockIdx.x * 256 + threadIdx.x) * 4;
    int c = (idx >> 14) & 255;
    int b = idx >> 22;
    int grp = b * NH_ + (c >> 5);
    const float invN = 1.0f / (float)(HD_ * HW_);
    float mu = stats[grp * 2 + 0] * invN;
    float var = stats[grp * 2 + 1] * invN - mu * mu;
    float r = rsqrtf(var + 1e-5f);
    float g = gamma[c], be = beta[c];
    float4 v = *(const float4*)&out[idx];
    float4 xv = *(const float4*)&x[idx];
    float4 o;
    o.x = xv.x + (v.x - mu) * r * g + be;
    o.y = xv.y + (v.y - mu) * r * g + be;
    o.z = xv.z + (v.z - mu) * r * g + be;
    o.w = xv.w + (v.w - mu) * r * g + be;
    *(float4*)&out[idx] = o;
}

extern "C" void kernel_launch(void* const* d_in, const int* in_sizes, int n_in,
                              void* d_out, int out_size, void* d_ws, size_t ws_size,
                              hipStream_t stream) {
    const float* x     = (const float*)d_in[0];
    const float* dww   = (const float*)d_in[1];
    const float* offw  = (const float*)d_in[2];
    const float* offb  = (const float*)d_in[3];
    const float* vw    = (const float*)d_in[4];
    const float* ow    = (const float*)d_in[5];
    const float* gamma = (const float*)d_in[6];
    const float* beta  = (const float*)d_in[7];
    float* out = (float*)d_out;
    float* ws_f = (float*)d_ws;

    // ws layout (floats)
    float* partials = ws_f;                                   // 16,777,216 f
    float* off_buf  = ws_f + 16777216;                        //  2,097,152 f
    float* stats    = ws_f + 18874368;                        //        256 f
    __hip_bfloat16* wvb = (__hip_bfloat16*)(ws_f + 18874624); //  65,536 bf16
    __hip_bfloat16* wob = wvb + 65536;                        //  65,536 bf16
    __hip_bfloat16* xT  = (__hip_bfloat16*)(ws_f + 18940160); //  33,554,432 bf16
    __hip_bfloat16* sT  = (__hip_bfloat16*)partials;          //  alias region A (partials dead after offreduce)
    __hip_bfloat16* vT  = (__hip_bfloat16*)out;               //  V^T bf16 staging in d_out (64MB of 128MB)

    // 1. weight converts + x transpose to bf16
    wconv_kernel<<<256, 256, 0, stream>>>(vw, ow, wvb, wob);
    xt_kernel<<<dim3(256, 4, 8), 256, 0, stream>>>(x, xT);
    // 2. fused dwconv + partial offset proj
    fused_offset_kernel<<<dim3(16, 8, 8), 256, 0, stream>>>(x, dww, offw, partials);
    offreduce_kernel<<<8192, 256, 0, stream>>>(partials, offb, off_buf);
    // 3. V^T[b][p][c] = (vw * x)^T bf16 (zero-LDS streaming MFMA GEMM)
    mfma_gemm<true, false><<<dim3(128, 2, 8), 256, 0, stream>>>(wvb, xT, (void*)vT, nullptr);
    // 4. deformable sampling from V^T bf16 -> sT bf16 [p][c]
    sample_kernel<<<dim3(2048, 1, 8), 256, 0, stream>>>(vT, off_buf, sT);
    // 5. out = ow * sampled + fused group stats -> d_out fp32
    hipMemsetAsync(stats, 0, 128 * sizeof(float), stream);
    mfma_gemm<false, true><<<dim3(128, 2, 8), 256, 0, stream>>>(wob, sT, (void*)out, stats);
    // 6. normalize + residual
    final_kernel<<<NTOT / 1024, 256, 0, stream>>>(x, stats, gamma, beta, out);
}

// Round 6
// 572.095 us; speedup vs baseline: 1.2031x; 1.1221x over previous
//
#include <hip/hip_runtime.h>
#include <hip/hip_bf16.h>

#define B_ 8
#define C_ 256
#define H_ 128
#define W_ 128
#define HW_ 16384
#define CHW_ (C_ * HW_)
#define NH_ 8
#define HD_ 32
#define NTOT (B_ * CHW_)   // 33,554,432

typedef short short8 __attribute__((ext_vector_type(8)));
typedef float f32x4 __attribute__((ext_vector_type(4)));

// ---------------- weight fp32 -> bf16 convert ----------------
__global__ __launch_bounds__(256) void wconv_kernel(const float* __restrict__ vw,
                                                    const float* __restrict__ ow,
                                                    __hip_bfloat16* __restrict__ wvb,
                                                    __hip_bfloat16* __restrict__ wob) {
    int i = blockIdx.x * 256 + threadIdx.x;   // 65536
    wvb[i] = __float2bfloat16(vw[i]);
    wob[i] = __float2bfloat16(ow[i]);
}

// ---------------- x [b][c][p] fp32 -> xT [b][p][c] bf16 (LDS-tiled transpose) ----------------
__global__ __launch_bounds__(256) void xt_kernel(const float* __restrict__ x,
                                                 __hip_bfloat16* __restrict__ xT) {
    __shared__ float tile[64][68];
    int t = threadIdx.x;
    int p0 = blockIdx.x * 64, c0 = blockIdx.y * 64, b = blockIdx.z;
    const float* xb = x + ((size_t)b * C_ + c0) * HW_ + p0;
#pragma unroll
    for (int l = 0; l < 4; ++l) {
        int idx = t + 256 * l;
        int row = idx >> 4, cf = idx & 15;
        float4 v = *(const float4*)&xb[(size_t)row * HW_ + cf * 4];
        *(float4*)&tile[row][cf * 4] = v;
    }
    __syncthreads();
    __hip_bfloat16* op = xT + ((size_t)b * HW_ + p0) * C_ + c0;
#pragma unroll
    for (int l = 0; l < 2; ++l) {
        int idx = t + 256 * l;
        int p = idx & 63, oct = idx >> 6;    // oct 0..7
        __hip_bfloat16 arr[8];
#pragma unroll
        for (int j = 0; j < 8; ++j) arr[j] = __float2bfloat16(tile[oct * 8 + j][p]);
        *(int4*)(op + (size_t)p * C_ + oct * 8) = *(int4*)arr;
    }
}

// ---------------- FUSED dwconv3x3 + partial offset projection ----------------
__global__ __launch_bounds__(256) void fused_offset_kernel(const float* __restrict__ x,
                                                           const float* __restrict__ dww,
                                                           const float* __restrict__ offw,
                                                           float* __restrict__ partials) {
    __shared__ float xt[4][10][136];   // 4 ch, 10 halo rows, col+4 shift, pad
    __shared__ float wT[32][16];
    __shared__ float wd[32][9];
    int t = threadIdx.x;
    int rt = blockIdx.x, cg = blockIdx.y, b = blockIdx.z;
    int h0 = rt * 8, c0 = cg * 32;
    for (int i = t; i < 512; i += 256) { int o = i >> 5, c = i & 31; wT[c][o] = offw[o * 256 + c0 + c]; }
    for (int i = t; i < 288; i += 256) { wd[i / 9][i % 9] = dww[(c0 + i / 9) * 9 + i % 9]; }
    const float* xb = x + ((size_t)b * C_ + c0) * HW_;
    int col = t & 127;
    int sb = (t >> 7) * 4;             // row-strip base 0 or 4
    float acc[4][16] = {};
    for (int cc0 = 0; cc0 < 32; cc0 += 4) {
        __syncthreads();
#pragma unroll
        for (int l = 0; l < 5; ++l) {
            int idx = t + 256 * l;             // 0..1279
            int pr = idx >> 5, c4 = idx & 31;
            int cc = pr / 10, r = pr - cc * 10;
            int gh = h0 - 1 + r;
            float4 v = make_float4(0.f, 0.f, 0.f, 0.f);
            if (gh >= 0 && gh < H_)
                v = *(const float4*)&xb[(size_t)(cc0 + cc) * HW_ + gh * W_ + c4 * 4];
            *(float4*)&xt[cc][r][4 + c4 * 4] = v;
        }
        if (t < 80) { int pr = t >> 1, side = t & 1; xt[pr / 10][pr % 10][side ? 132 : 3] = 0.f; }
        __syncthreads();
#pragma unroll
        for (int cc = 0; cc < 4; ++cc) {
            float win[6][3];
#pragma unroll
            for (int rr = 0; rr < 6; ++rr)
#pragma unroll
                for (int kk = 0; kk < 3; ++kk)
                    win[rr][kk] = xt[cc][sb + rr][col + 3 + kk];
            float w9[9];
#pragma unroll
            for (int k9 = 0; k9 < 9; ++k9) w9[k9] = wd[cc0 + cc][k9];
#pragma unroll
            for (int j = 0; j < 4; ++j) {
                float s = 0.f;
#pragma unroll
                for (int ky = 0; ky < 3; ++ky)
#pragma unroll
                    for (int kx = 0; kx < 3; ++kx)
                        s += win[j + ky][kx] * w9[ky * 3 + kx];
#pragma unroll
                for (int o = 0; o < 16; ++o) acc[j][o] += s * wT[cc0 + cc][o];
            }
        }
    }
    float* pb = partials + (size_t)(cg * 8 + b) * 16 * HW_;
#pragma unroll
    for (int o = 0; o < 16; ++o)
#pragma unroll
        for (int j = 0; j < 4; ++j)
            pb[(size_t)o * HW_ + (h0 + sb + j) * W_ + col] = acc[j][o];
}

// ---------------- sum 8 partials + bias + tanh ----------------
__global__ __launch_bounds__(256) void offreduce_kernel(const float* __restrict__ partials,
                                                        const float* __restrict__ offb,
                                                        float* __restrict__ off_buf) {
    int i = blockIdx.x * 256 + threadIdx.x;     // 0..2097151 over [b][o][p]
    float s = 0.f;
#pragma unroll
    for (int cg = 0; cg < 8; ++cg) s += partials[(size_t)cg * 2097152 + i];
    int o = (i >> 14) & 15;
    off_buf[i] = tanhf(s + offb[o]) * 0.5f;
}

// ---------------- bf16 MFMA GEMM: Y[b](256 x HW) = W(256x256) * X[b], X given as X^T [p][c] ----------------
// m97-structure: single-buffered LDS (A[128][32] + B[128][32] bf16, linear 64B rows), staged via
// global_load_lds width=16 DMA (no VGPR round-trip -> compiler can't de-pipeline it).
// Bank conflicts: LDS stays LINEAR for the DMA; the global SOURCE is pre-swizzled with
// slot ^= (row>>1)&3 and ds_read applies the same XOR (both-sides involution, rule #21).
// 2 barriers per K-step, 8 steps.
// TRANS: write Y^T [n][c] as bf16 (for sampling).  STATS: accumulate group sum/sumsq.
template<bool TRANS, bool STATS>
__global__ __launch_bounds__(256, 4) void mfma_gemm(const __hip_bfloat16* __restrict__ Wb,
                                                    const __hip_bfloat16* __restrict__ Xt,
                                                    void* __restrict__ Y,
                                                    float* __restrict__ stats) {
    __shared__ __align__(16) short As[128 * 32];   // 8KB, [row][slot] 64B rows, 4x16B slots
    __shared__ __align__(16) short Bs[128 * 32];   // 8KB
    int t = threadIdx.x;
    int wave = t >> 6, lane = t & 63;
    int quad = lane >> 4, l16 = lane & 15;
    int b = blockIdx.z;
    int n0 = blockIdx.x * 128, m0 = blockIdx.y * 128;
    const short* Wp = (const short*)Wb + (size_t)m0 * 256;
    const short* Xp = (const short*)Xt + ((size_t)b * HW_ + n0) * 256;

    // staging coords: 512 chunks of 16B per tile, 2 per thread; chunk i -> row i>>2, slot i&3.
    // LDS dest is linear (i*16B, lane-linear within wave); global src slot is XOR-swizzled.
    int i0 = t, i1 = t + 256;
    int r0 = i0 >> 2, r1 = i1 >> 2;
    int ss0 = (i0 & 3) ^ ((r0 >> 1) & 3);
    int ss1 = (i1 & 3) ^ ((r1 >> 1) & 3);

    f32x4 acc[2][8];
#pragma unroll
    for (int mt = 0; mt < 2; ++mt)
#pragma unroll
        for (int nt = 0; nt < 8; ++nt) acc[mt][nt] = (f32x4){0.f, 0.f, 0.f, 0.f};

    for (int kk = 0; kk < 8; ++kk) {
        int ko = kk * 32;
        __builtin_amdgcn_global_load_lds(Wp + (size_t)r0 * 256 + ko + ss0 * 8, &As[i0 * 8], 16, 0, 0);
        __builtin_amdgcn_global_load_lds(Wp + (size_t)r1 * 256 + ko + ss1 * 8, &As[i1 * 8], 16, 0, 0);
        __builtin_amdgcn_global_load_lds(Xp + (size_t)r0 * 256 + ko + ss0 * 8, &Bs[i0 * 8], 16, 0, 0);
        __builtin_amdgcn_global_load_lds(Xp + (size_t)r1 * 256 + ko + ss1 * 8, &Bs[i1 * 8], 16, 0, 0);
        __syncthreads();    // compiler emits vmcnt(0) drain here (m97 structural cost, proven OK)
        short8 af[2], bf[8];
#pragma unroll
        for (int mt = 0; mt < 2; ++mt) {
            int r = wave * 32 + mt * 16 + l16;
            int sl = quad ^ ((r >> 1) & 3);
            af[mt] = *(const short8*)&As[r * 32 + sl * 8];
        }
#pragma unroll
        for (int nt = 0; nt < 8; ++nt) {
            int r = nt * 16 + l16;
            int sl = quad ^ ((r >> 1) & 3);
            bf[nt] = *(const short8*)&Bs[r * 32 + sl * 8];
        }
#pragma unroll
        for (int mt = 0; mt < 2; ++mt)
#pragma unroll
            for (int nt = 0; nt < 8; ++nt)
                acc[mt][nt] = __builtin_amdgcn_mfma_f32_16x16x32_bf16(af[mt], bf[nt], acc[mt][nt], 0, 0, 0);
        __syncthreads();
    }

    if constexpr (TRANS) {
        // Y^T [n][c] bf16: acc[mt][nt] = 4 consecutive channels at one n -> 8B store
        __hip_bfloat16* Yb = (__hip_bfloat16*)Y + (size_t)b * CHW_;
#pragma unroll
        for (int mt = 0; mt < 2; ++mt)
#pragma unroll
            for (int nt = 0; nt < 8; ++nt) {
                int m = m0 + wave * 32 + mt * 16 + quad * 4;
                int n = n0 + nt * 16 + l16;
                __hip_bfloat16 arr[4];
#pragma unroll
                for (int r = 0; r < 4; ++r) arr[r] = __float2bfloat16(acc[mt][nt][r]);
                *(int2*)((__hip_bfloat16*)Yb + (size_t)n * C_ + m) = *(int2*)arr;
            }
    } else {
        float* Yb = (float*)Y + (size_t)b * CHW_;
#pragma unroll
        for (int mt = 0; mt < 2; ++mt)
#pragma unroll
            for (int nt = 0; nt < 8; ++nt)
#pragma unroll
                for (int r = 0; r < 4; ++r) {
                    int m = m0 + wave * 32 + mt * 16 + quad * 4 + r;
                    int n = n0 + nt * 16 + l16;
                    Yb[(size_t)m * HW_ + n] = acc[mt][nt][r];
                }
    }
    if constexpr (STATS) {
        // each wave's m-range is exactly one 32-channel group: grp = b*8 + m0/32 + wave
        float s1 = 0.f, s2 = 0.f;
#pragma unroll
        for (int mt = 0; mt < 2; ++mt)
#pragma unroll
            for (int nt = 0; nt < 8; ++nt)
#pragma unroll
                for (int r = 0; r < 4; ++r) {
                    float v = acc[mt][nt][r];
                    s1 += v;
                    s2 += v * v;
                }
#pragma unroll
        for (int o = 32; o; o >>= 1) {
            s1 += __shfl_down(s1, o);
            s2 += __shfl_down(s2, o);
        }
        if (lane == 0) {
            int grp = b * NH_ + (m0 >> 5) + wave;
            atomicAdd(&stats[grp * 2 + 0], s1);
            atomicAdd(&stats[grp * 2 + 1], s2);
        }
    }
}

// ---------------- deformable bilinear sampling from V^T bf16 [b][p][c] -> sampledT bf16 [b][p][c] ----------------
// block 256 = 8 pixels x 8 heads x 4 chunks; 4 consecutive lanes = the 4x16B bf16 chunks of one
// (pixel,head) 64B tap segment -> every load reads contiguous 64B lines.
__global__ __launch_bounds__(256) void sample_kernel(const __hip_bfloat16* __restrict__ VT,
                                                     const float* __restrict__ off,
                                                     __hip_bfloat16* __restrict__ sT) {
    int t = threadIdx.x;
    int chunk = t & 3;                 // 16B (8ch) chunk within head's 64B segment
    int g = t >> 2;                    // 0..63 = pixel_sub*8 + head
    int head = g & 7;
    int p = blockIdx.x * 8 + (g >> 3);
    int b = blockIdx.z;
    int h = p >> 7, w = p & 127;
    const float* ob = off + ((size_t)b * 16 + head * 2) * HW_ + p;
    float dy = ob[0], dx = ob[HW_];    // broadcast within 4-lane group
    float gy = h * (2.0f / 127.0f) - 1.0f;
    float gx = w * (2.0f / 127.0f) - 1.0f;
    float sx = fminf(fmaxf(gx + dx, -1.0f), 1.0f);
    float sy = fminf(fmaxf(gy + dy, -1.0f), 1.0f);
    float ix = (sx + 1.0f) * 0.5f * 127.0f;
    float iy = (sy + 1.0f) * 0.5f * 127.0f;
    float x0f = floorf(ix), y0f = floorf(iy);
    float wx = ix - x0f, wy = iy - y0f;
    int x0 = min(max((int)x0f, 0), 127);
    int x1 = min((int)x0f + 1, 127);
    int y0 = min(max((int)y0f, 0), 127);
    int y1 = min((int)y0f + 1, 127);
    float w00 = (1.f - wx) * (1.f - wy), w01 = wx * (1.f - wy);
    float w10 = (1.f - wx) * wy, w11 = wx * wy;
    const short* Vb = (const short*)VT + (size_t)b * CHW_ + head * 32 + chunk * 8;
    short8 v00 = *(const short8*)(Vb + (size_t)(y0 * W_ + x0) * C_);
    short8 v01 = *(const short8*)(Vb + (size_t)(y0 * W_ + x1) * C_);
    short8 v10 = *(const short8*)(Vb + (size_t)(y1 * W_ + x0) * C_);
    short8 v11 = *(const short8*)(Vb + (size_t)(y1 * W_ + x1) * C_);
    __hip_bfloat16 arr[8];
#pragma unroll
    for (int j = 0; j < 8; ++j) {
        float f = __bfloat162float(((const __hip_bfloat16*)&v00)[j]) * w00 +
                  __bfloat162float(((const __hip_bfloat16*)&v01)[j]) * w01 +
                  __bfloat162float(((const __hip_bfloat16*)&v10)[j]) * w10 +
                  __bfloat162float(((const __hip_bfloat16*)&v11)[j]) * w11;
        arr[j] = __float2bfloat16(f);
    }
    __hip_bfloat16* op = sT + ((size_t)b * HW_ + p) * C_ + head * 32 + chunk * 8;
    *(int4*)op = *(int4*)arr;
}

// ---------------- normalize + affine + residual (float4) ----------------
__global__ __launch_bounds__(256) void final_kernel(const float* __restrict__ x,
                                                    const float* __restrict__ stats,
                                                    const float* __restrict__ gamma,
                                                    const float* __restrict__ beta,
                                                    float* __restrict__ out) {
    int idx = (blockIdx.x * 256 + threadIdx.x) * 4;
    int c = (idx >> 14) & 255;
    int b = idx >> 22;
    int grp = b * NH_ + (c >> 5);
    const float invN = 1.0f / (float)(HD_ * HW_);
    float mu = stats[grp * 2 + 0] * invN;
    float var = stats[grp * 2 + 1] * invN - mu * mu;
    float r = rsqrtf(var + 1e-5f);
    float g = gamma[c], be = beta[c];
    float4 v = *(const float4*)&out[idx];
    float4 xv = *(const float4*)&x[idx];
    float4 o;
    o.x = xv.x + (v.x - mu) * r * g + be;
    o.y = xv.y + (v.y - mu) * r * g + be;
    o.z = xv.z + (v.z - mu) * r * g + be;
    o.w = xv.w + (v.w - mu) * r * g + be;
    *(float4*)&out[idx] = o;
}

extern "C" void kernel_launch(void* const* d_in, const int* in_sizes, int n_in,
                              void* d_out, int out_size, void* d_ws, size_t ws_size,
                              hipStream_t stream) {
    const float* x     = (const float*)d_in[0];
    const float* dww   = (const float*)d_in[1];
    const float* offw  = (const float*)d_in[2];
    const float* offb  = (const float*)d_in[3];
    const float* vw    = (const float*)d_in[4];
    const float* ow    = (const float*)d_in[5];
    const float* gamma = (const float*)d_in[6];
    const float* beta  = (const float*)d_in[7];
    float* out = (float*)d_out;
    float* ws_f = (float*)d_ws;

    // ws layout (floats)
    float* partials = ws_f;                                   // 16,777,216 f
    float* off_buf  = ws_f + 16777216;                        //  2,097,152 f
    float* stats    = ws_f + 18874368;                        //        256 f
    __hip_bfloat16* wvb = (__hip_bfloat16*)(ws_f + 18874624); //  65,536 bf16
    __hip_bfloat16* wob = wvb + 65536;                        //  65,536 bf16
    __hip_bfloat16* xT  = (__hip_bfloat16*)(ws_f + 18940160); //  33,554,432 bf16
    __hip_bfloat16* sT  = (__hip_bfloat16*)partials;          //  alias region A (partials dead after offreduce)
    __hip_bfloat16* vT  = (__hip_bfloat16*)out;               //  V^T bf16 staging in d_out (64MB of 128MB)

    // 1. weight converts + x transpose to bf16
    wconv_kernel<<<256, 256, 0, stream>>>(vw, ow, wvb, wob);
    xt_kernel<<<dim3(256, 4, 8), 256, 0, stream>>>(x, xT);
    // 2. fused dwconv + partial offset proj
    fused_offset_kernel<<<dim3(16, 8, 8), 256, 0, stream>>>(x, dww, offw, partials);
    offreduce_kernel<<<8192, 256, 0, stream>>>(partials, offb, off_buf);
    // 3. V^T[b][p][c] = (vw * x)^T bf16 (global_load_lds MFMA GEMM)
    mfma_gemm<true, false><<<dim3(128, 2, 8), 256, 0, stream>>>(wvb, xT, (void*)vT, nullptr);
    // 4. deformable sampling from V^T bf16 -> sT bf16 [p][c]
    sample_kernel<<<dim3(2048, 1, 8), 256, 0, stream>>>(vT, off_buf, sT);
    // 5. out = ow * sampled + fused group stats -> d_out fp32
    hipMemsetAsync(stats, 0, 128 * sizeof(float), stream);
    mfma_gemm<false, true><<<dim3(128, 2, 8), 256, 0, stream>>>(wob, sT, (void*)out, stats);
    // 6. normalize + residual
    final_kernel<<<NTOT / 1024, 256, 0, stream>>>(x, stats, gamma, beta, out);
}

// Round 8
// 558.340 us; speedup vs baseline: 1.2327x; 1.0246x over previous
//
#include <hip/hip_runtime.h>
#include <hip/hip_bf16.h>

#define B_ 8
#define C_ 256
#define H_ 128
#define W_ 128
#define HW_ 16384
#define CHW_ (C_ * HW_)
#define NH_ 8
#define HD_ 32
#define NTOT (B_ * CHW_)   // 33,554,432

typedef short short8 __attribute__((ext_vector_type(8)));
typedef float f32x4 __attribute__((ext_vector_type(4)));

// ---------------- weight fp32 -> bf16 convert ----------------
__global__ __launch_bounds__(256) void wconv_kernel(const float* __restrict__ vw,
                                                    const float* __restrict__ ow,
                                                    __hip_bfloat16* __restrict__ wvb,
                                                    __hip_bfloat16* __restrict__ wob) {
    int i = blockIdx.x * 256 + threadIdx.x;   // 65536
    wvb[i] = __float2bfloat16(vw[i]);
    wob[i] = __float2bfloat16(ow[i]);
}

// ---------------- x [b][c][p] fp32 -> xT [b][p][c] bf16 (LDS-tiled transpose) ----------------
__global__ __launch_bounds__(256) void xt_kernel(const float* __restrict__ x,
                                                 __hip_bfloat16* __restrict__ xT) {
    __shared__ float tile[64][68];
    int t = threadIdx.x;
    int p0 = blockIdx.x * 64, c0 = blockIdx.y * 64, b = blockIdx.z;
    const float* xb = x + ((size_t)b * C_ + c0) * HW_ + p0;
#pragma unroll
    for (int l = 0; l < 4; ++l) {
        int idx = t + 256 * l;
        int row = idx >> 4, cf = idx & 15;
        float4 v = *(const float4*)&xb[(size_t)row * HW_ + cf * 4];
        *(float4*)&tile[row][cf * 4] = v;
    }
    __syncthreads();
    __hip_bfloat16* op = xT + ((size_t)b * HW_ + p0) * C_ + c0;
#pragma unroll
    for (int l = 0; l < 2; ++l) {
        int idx = t + 256 * l;
        int p = idx & 63, oct = idx >> 6;    // oct 0..7
        __hip_bfloat16 arr[8];
#pragma unroll
        for (int j = 0; j < 8; ++j) arr[j] = __float2bfloat16(tile[oct * 8 + j][p]);
        *(int4*)(op + (size_t)p * C_ + oct * 8) = *(int4*)arr;
    }
}

// ---------------- FUSED dwconv3x3 + partial offset projection ----------------
__global__ __launch_bounds__(256) void fused_offset_kernel(const float* __restrict__ x,
                                                           const float* __restrict__ dww,
                                                           const float* __restrict__ offw,
                                                           float* __restrict__ partials) {
    __shared__ float xt[4][10][136];   // 4 ch, 10 halo rows, col+4 shift, pad
    __shared__ float wT[32][16];
    __shared__ float wd[32][9];
    int t = threadIdx.x;
    int rt = blockIdx.x, cg = blockIdx.y, b = blockIdx.z;
    int h0 = rt * 8, c0 = cg * 32;
    for (int i = t; i < 512; i += 256) { int o = i >> 5, c = i & 31; wT[c][o] = offw[o * 256 + c0 + c]; }
    for (int i = t; i < 288; i += 256) { wd[i / 9][i % 9] = dww[(c0 + i / 9) * 9 + i % 9]; }
    const float* xb = x + ((size_t)b * C_ + c0) * HW_;
    int col = t & 127;
    int sb = (t >> 7) * 4;             // row-strip base 0 or 4
    float acc[4][16] = {};
    for (int cc0 = 0; cc0 < 32; cc0 += 4) {
        __syncthreads();
#pragma unroll
        for (int l = 0; l < 5; ++l) {
            int idx = t + 256 * l;             // 0..1279
            int pr = idx >> 5, c4 = idx & 31;
            int cc = pr / 10, r = pr - cc * 10;
            int gh = h0 - 1 + r;
            float4 v = make_float4(0.f, 0.f, 0.f, 0.f);
            if (gh >= 0 && gh < H_)
                v = *(const float4*)&xb[(size_t)(cc0 + cc) * HW_ + gh * W_ + c4 * 4];
            *(float4*)&xt[cc][r][4 + c4 * 4] = v;
        }
        if (t < 80) { int pr = t >> 1, side = t & 1; xt[pr / 10][pr % 10][side ? 132 : 3] = 0.f; }
        __syncthreads();
#pragma unroll
        for (int cc = 0; cc < 4; ++cc) {
            float win[6][3];
#pragma unroll
            for (int rr = 0; rr < 6; ++rr)
#pragma unroll
                for (int kk = 0; kk < 3; ++kk)
                    win[rr][kk] = xt[cc][sb + rr][col + 3 + kk];
            float w9[9];
#pragma unroll
            for (int k9 = 0; k9 < 9; ++k9) w9[k9] = wd[cc0 + cc][k9];
#pragma unroll
            for (int j = 0; j < 4; ++j) {
                float s = 0.f;
#pragma unroll
                for (int ky = 0; ky < 3; ++ky)
#pragma unroll
                    for (int kx = 0; kx < 3; ++kx)
                        s += win[j + ky][kx] * w9[ky * 3 + kx];
#pragma unroll
                for (int o = 0; o < 16; ++o) acc[j][o] += s * wT[cc0 + cc][o];
            }
        }
    }
    float* pb = partials + (size_t)(cg * 8 + b) * 16 * HW_;
#pragma unroll
    for (int o = 0; o < 16; ++o)
#pragma unroll
        for (int j = 0; j < 4; ++j)
            pb[(size_t)o * HW_ + (h0 + sb + j) * W_ + col] = acc[j][o];
}

// ---------------- sum 8 partials + bias + tanh ----------------
__global__ __launch_bounds__(256) void offreduce_kernel(const float* __restrict__ partials,
                                                        const float* __restrict__ offb,
                                                        float* __restrict__ off_buf) {
    int i = blockIdx.x * 256 + threadIdx.x;     // 0..2097151 over [b][o][p]
    float s = 0.f;
#pragma unroll
    for (int cg = 0; cg < 8; ++cg) s += partials[(size_t)cg * 2097152 + i];
    int o = (i >> 14) & 15;
    off_buf[i] = tanhf(s + offb[o]) * 0.5f;
}

// ---------------- bf16 MFMA GEMM: Y[b](256 x HW) = W(256x256) * X[b], X given as X^T [p][c] ----------------
// T3 2-phase double-buffered structure on the m97 DMA skeleton:
//  - global_load_lds width=16 staging (no VGPR round-trip -> compiler can't de-pipeline).
//  - DOUBLE-buffered A/B tiles; the NEXT k-step's DMAs are issued BEFORE computing the current
//    step, so the vmcnt(0) drain that __syncthreads emits lands AFTER compute covered the latency.
//    ONE barrier per K-step.  sched_barrier(0) pins the DMA issue before the ds_reads.
//  - Bank conflicts: LDS linear for DMA; global SOURCE slot pre-swizzled (slot ^= (row>>1)&3),
//    ds_read applies the same XOR (both-sides involution).
//  - TRANS epilogue stages the output tile in LDS (row stride 136 = conflict-free) and writes
//    fully-coalesced 256B row segments (kills the 2.8x write amplification of strided 8B stores).
// TRANS: write Y^T [n][c] as bf16 (for sampling).  STATS: accumulate group sum/sumsq.
template<bool TRANS, bool STATS>
__global__ __launch_bounds__(256, 4) void mfma_gemm(const __hip_bfloat16* __restrict__ Wb,
                                                    const __hip_bfloat16* __restrict__ Xt,
                                                    void* __restrict__ Y,
                                                    float* __restrict__ stats) {
    // 17408 shorts = 34,816 B:
    //   stage: A dbuf [2][4096] at 0, B dbuf [2][4096] at 8192   (each tile 128 rows x 32 k)
    //   TRANS epilogue reuse: [128 rows][136 stride] bf16 output tile
    __shared__ __align__(16) short smem[17408];
    int t = threadIdx.x;
    int wave = t >> 6, lane = t & 63;
    int quad = lane >> 4, l16 = lane & 15;
    int b = blockIdx.z;
    int n0 = blockIdx.x * 128, m0 = blockIdx.y * 128;
    const short* Wp = (const short*)Wb + (size_t)m0 * 256;
    const short* Xp = (const short*)Xt + ((size_t)b * HW_ + n0) * 256;

    // staging coords: 512 chunks of 16B per tile, 2 per thread; chunk i -> row i>>2, slot i&3.
    // LDS dest is lane-linear (DMA semantics); global src slot is XOR-swizzled.
    int i0 = t, i1 = t + 256;
    int r0 = i0 >> 2, r1 = i1 >> 2;
    int ss0 = (i0 & 3) ^ ((r0 >> 1) & 3);
    int ss1 = (i1 & 3) ^ ((r1 >> 1) & 3);

#define STAGE(buf, ko)                                                                                          \
    do {                                                                                                        \
        short* Asm_ = smem + (buf) * 4096;                                                                      \
        short* Bsm_ = smem + 8192 + (buf) * 4096;                                                               \
        __builtin_amdgcn_global_load_lds(Wp + (size_t)r0 * 256 + (ko) + ss0 * 8, Asm_ + i0 * 8, 16, 0, 0);      \
        __builtin_amdgcn_global_load_lds(Wp + (size_t)r1 * 256 + (ko) + ss1 * 8, Asm_ + i1 * 8, 16, 0, 0);      \
        __builtin_amdgcn_global_load_lds(Xp + (size_t)r0 * 256 + (ko) + ss0 * 8, Bsm_ + i0 * 8, 16, 0, 0);      \
        __builtin_amdgcn_global_load_lds(Xp + (size_t)r1 * 256 + (ko) + ss1 * 8, Bsm_ + i1 * 8, 16, 0, 0);      \
    } while (0)

    f32x4 acc[2][8];
#pragma unroll
    for (int mt = 0; mt < 2; ++mt)
#pragma unroll
        for (int nt = 0; nt < 8; ++nt) acc[mt][nt] = (f32x4){0.f, 0.f, 0.f, 0.f};

    STAGE(0, 0);
    __syncthreads();                       // drain prologue stage

#pragma unroll
    for (int kk = 0; kk < 8; ++kk) {
        int cur = kk & 1;
        if (kk < 7) STAGE(cur ^ 1, (kk + 1) * 32);   // prefetch next tile BEFORE compute
        __builtin_amdgcn_sched_barrier(0);            // pin DMA issue above the ds_reads
        const short* Ac = smem + cur * 4096;
        const short* Bc = smem + 8192 + cur * 4096;
        short8 af[2], bf[8];
#pragma unroll
        for (int mt = 0; mt < 2; ++mt) {
            int r = wave * 32 + mt * 16 + l16;
            int sl = quad ^ ((r >> 1) & 3);
            af[mt] = *(const short8*)&Ac[r * 32 + sl * 8];
        }
#pragma unroll
        for (int nt = 0; nt < 8; ++nt) {
            int r = nt * 16 + l16;
            int sl = quad ^ ((r >> 1) & 3);
            bf[nt] = *(const short8*)&Bc[r * 32 + sl * 8];
        }
#pragma unroll
        for (int mt = 0; mt < 2; ++mt)
#pragma unroll
            for (int nt = 0; nt < 8; ++nt)
                acc[mt][nt] = __builtin_amdgcn_mfma_f32_16x16x32_bf16(af[mt], bf[nt], acc[mt][nt], 0, 0, 0);
        __syncthreads();                   // ONE barrier/step: drains prefetch (issued pre-compute)
    }
#undef STAGE

    if constexpr (TRANS) {
        // stage output tile [n][m] bf16 in LDS (stride 136), then coalesced 256B row writes
#pragma unroll
        for (int mt = 0; mt < 2; ++mt)
#pragma unroll
            for (int nt = 0; nt < 8; ++nt) {
                int n = nt * 16 + l16;
                int mloc = wave * 32 + mt * 16 + quad * 4;
                __hip_bfloat16 arr[4];
#pragma unroll
                for (int r = 0; r < 4; ++r) arr[r] = __float2bfloat16(acc[mt][nt][r]);
                *(int2*)&smem[n * 136 + mloc] = *(int2*)arr;
            }
        __syncthreads();
        short* Yb = (short*)Y + (size_t)b * CHW_;
#pragma unroll
        for (int i = 0; i < 8; ++i) {
            int id = t + 256 * i;          // 0..2047: 128 rows x 16 chunks
            int row = id >> 4, c = id & 15;
            int4 v = *(const int4*)&smem[row * 136 + c * 8];
            *(int4*)(Yb + (size_t)(n0 + row) * 256 + m0 + c * 8) = v;
        }
    } else {
        float* Yb = (float*)Y + (size_t)b * CHW_;
#pragma unroll
        for (int mt = 0; mt < 2; ++mt)
#pragma unroll
            for (int nt = 0; nt < 8; ++nt)
#pragma unroll
                for (int r = 0; r < 4; ++r) {
                    int m = m0 + wave * 32 + mt * 16 + quad * 4 + r;
                    int n = n0 + nt * 16 + l16;
                    Yb[(size_t)m * HW_ + n] = acc[mt][nt][r];
                }
    }
    if constexpr (STATS) {
        // each wave's m-range is exactly one 32-channel group: grp = b*8 + m0/32 + wave
        float s1 = 0.f, s2 = 0.f;
#pragma unroll
        for (int mt = 0; mt < 2; ++mt)
#pragma unroll
            for (int nt = 0; nt < 8; ++nt)
#pragma unroll
                for (int r = 0; r < 4; ++r) {
                    float v = acc[mt][nt][r];
                    s1 += v;
                    s2 += v * v;
                }
#pragma unroll
        for (int o = 32; o; o >>= 1) {
            s1 += __shfl_down(s1, o);
            s2 += __shfl_down(s2, o);
        }
        if (lane == 0) {
            int grp = b * NH_ + (m0 >> 5) + wave;
            atomicAdd(&stats[grp * 2 + 0], s1);
            atomicAdd(&stats[grp * 2 + 1], s2);
        }
    }
}

// ---------------- deformable bilinear sampling from V^T bf16 [b][p][c] -> sampledT bf16 [b][p][c] ----------------
// block 256 = 8 pixels x 8 heads x 4 chunks; 4 consecutive lanes = the 4x16B bf16 chunks of one
// (pixel,head) 64B tap segment -> every load reads contiguous 64B lines.
__global__ __launch_bounds__(256) void sample_kernel(const __hip_bfloat16* __restrict__ VT,
                                                     const float* __restrict__ off,
                                                     __hip_bfloat16* __restrict__ sT) {
    int t = threadIdx.x;
    int chunk = t & 3;                 // 16B (8ch) chunk within head's 64B segment
    int g = t >> 2;                    // 0..63 = pixel_sub*8 + head
    int head = g & 7;
    int p = blockIdx.x * 8 + (g >> 3);
    int b = blockIdx.z;
    int h = p >> 7, w = p & 127;
    const float* ob = off + ((size_t)b * 16 + head * 2) * HW_ + p;
    float dy = ob[0], dx = ob[HW_];    // broadcast within 4-lane group
    float gy = h * (2.0f / 127.0f) - 1.0f;
    float gx = w * (2.0f / 127.0f) - 1.0f;
    float sx = fminf(fmaxf(gx + dx, -1.0f), 1.0f);
    float sy = fminf(fmaxf(gy + dy, -1.0f), 1.0f);
    float ix = (sx + 1.0f) * 0.5f * 127.0f;
    float iy = (sy + 1.0f) * 0.5f * 127.0f;
    float x0f = floorf(ix), y0f = floorf(iy);
    float wx = ix - x0f, wy = iy - y0f;
    int x0 = min(max((int)x0f, 0), 127);
    int x1 = min((int)x0f + 1, 127);
    int y0 = min(max((int)y0f, 0), 127);
    int y1 = min((int)y0f + 1, 127);
    float w00 = (1.f - wx) * (1.f - wy), w01 = wx * (1.f - wy);
    float w10 = (1.f - wx) * wy, w11 = wx * wy;
    const short* Vb = (const short*)VT + (size_t)b * CHW_ + head * 32 + chunk * 8;
    short8 v00 = *(const short8*)(Vb + (size_t)(y0 * W_ + x0) * C_);
    short8 v01 = *(const short8*)(Vb + (size_t)(y0 * W_ + x1) * C_);
    short8 v10 = *(const short8*)(Vb + (size_t)(y1 * W_ + x0) * C_);
    short8 v11 = *(const short8*)(Vb + (size_t)(y1 * W_ + x1) * C_);
    __hip_bfloat16 arr[8];
#pragma unroll
    for (int j = 0; j < 8; ++j) {
        float f = __bfloat162float(((const __hip_bfloat16*)&v00)[j]) * w00 +
                  __bfloat162float(((const __hip_bfloat16*)&v01)[j]) * w01 +
                  __bfloat162float(((const __hip_bfloat16*)&v10)[j]) * w10 +
                  __bfloat162float(((const __hip_bfloat16*)&v11)[j]) * w11;
        arr[j] = __float2bfloat16(f);
    }
    __hip_bfloat16* op = sT + ((size_t)b * HW_ + p) * C_ + head * 32 + chunk * 8;
    *(int4*)op = *(int4*)arr;
}

// ---------------- normalize + affine + residual (float4) ----------------
__global__ __launch_bounds__(256) void final_kernel(const float* __restrict__ x,
                                                    const float* __restrict__ stats,
                                                    const float* __restrict__ gamma,
                                                    const float* __restrict__ beta,
                                                    float* __restrict__ out) {
    int idx = (blockIdx.x * 256 + threadIdx.x) * 4;
    int c = (idx >> 14) & 255;
    int b = idx >> 22;
    int grp = b * NH_ + (c >> 5);
    const float invN = 1.0f / (float)(HD_ * HW_);
    float mu = stats[grp * 2 + 0] * invN;
    float var = stats[grp * 2 + 1] * invN - mu * mu;
    float r = rsqrtf(var + 1e-5f);
    float g = gamma[c], be = beta[c];
    float4 v = *(const float4*)&out[idx];
    float4 xv = *(const float4*)&x[idx];
    float4 o;
    o.x = xv.x + (v.x - mu) * r * g + be;
    o.y = xv.y + (v.y - mu) * r * g + be;
    o.z = xv.z + (v.z - mu) * r * g + be;
    o.w = xv.w + (v.w - mu) * r * g + be;
    *(float4*)&out[idx] = o;
}

extern "C" void kernel_launch(void* const* d_in, const int* in_sizes, int n_in,
                              void* d_out, int out_size, void* d_ws, size_t ws_size,
                              hipStream_t stream) {
    const float* x     = (const float*)d_in[0];
    const float* dww   = (const float*)d_in[1];
    const float* offw  = (const float*)d_in[2];
    const float* offb  = (const float*)d_in[3];
    const float* vw    = (const float*)d_in[4];
    const float* ow    = (const float*)d_in[5];
    const float* gamma = (const float*)d_in[6];
    const float* beta  = (const float*)d_in[7];
    float* out = (float*)d_out;
    float* ws_f = (float*)d_ws;

    // ws layout (floats)
    float* partials = ws_f;                                   // 16,777,216 f
    float* off_buf  = ws_f + 16777216;                        //  2,097,152 f
    float* stats    = ws_f + 18874368;                        //        256 f
    __hip_bfloat16* wvb = (__hip_bfloat16*)(ws_f + 18874624); //  65,536 bf16
    __hip_bfloat16* wob = wvb + 65536;                        //  65,536 bf16
    __hip_bfloat16* xT  = (__hip_bfloat16*)(ws_f + 18940160); //  33,554,432 bf16
    __hip_bfloat16* sT  = (__hip_bfloat16*)partials;          //  alias region A (partials dead after offreduce)
    __hip_bfloat16* vT  = (__hip_bfloat16*)out;               //  V^T bf16 staging in d_out (64MB of 128MB)

    // 1. weight converts + x transpose to bf16
    wconv_kernel<<<256, 256, 0, stream>>>(vw, ow, wvb, wob);
    xt_kernel<<<dim3(256, 4, 8), 256, 0, stream>>>(x, xT);
    // 2. fused dwconv + partial offset proj
    fused_offset_kernel<<<dim3(16, 8, 8), 256, 0, stream>>>(x, dww, offw, partials);
    offreduce_kernel<<<8192, 256, 0, stream>>>(partials, offb, off_buf);
    // 3. V^T[b][p][c] = (vw * x)^T bf16 (2-phase double-buffered DMA GEMM)
    mfma_gemm<true, false><<<dim3(128, 2, 8), 256, 0, stream>>>(wvb, xT, (void*)vT, nullptr);
    // 4. deformable sampling from V^T bf16 -> sT bf16 [p][c]
    sample_kernel<<<dim3(2048, 1, 8), 256, 0, stream>>>(vT, off_buf, sT);
    // 5. out = ow * sampled + fused group stats -> d_out fp32
    hipMemsetAsync(stats, 0, 128 * sizeof(float), stream);
    mfma_gemm<false, true><<<dim3(128, 2, 8), 256, 0, stream>>>(wob, sT, (void*)out, stats);
    // 6. normalize + residual
    final_kernel<<<NTOT / 1024, 256, 0, stream>>>(x, stats, gamma, beta, out);
}